// Round 5
// baseline (532.907 us; speedup 1.0000x reference)
//
#include <hip/hip_runtime.h>
#include <stdint.h>

typedef unsigned short u16;
typedef unsigned int   u32;
typedef _Float16 f16;
typedef __attribute__((ext_vector_type(2))) _Float16 half2v;
typedef __attribute__((ext_vector_type(8))) _Float16 half8;   // 8 f16 = 4 VGPRs (MFMA A/B frag)
typedef __attribute__((ext_vector_type(4))) float f32x4;      // MFMA C/D frag

#define TPB 256           // 4 waves; 6 blocks/CU (LDS 24576B) = 24 waves/CU
#define FPB 16            // frames per block; 4000/16=250 -> blocks never straddle batches
#define NB 257
#define LF 513
#define FS 80
#define NCH 9             // K chunks of 32: slots 0..256 = H[0..256], 257..287 = 0
#define MT_TOTAL 33       // 33 tap tiles of 16 = 528 taps (513 real + 15 zero)
#define HROW16 296        // Hlds row stride (u16): 592B, 16B-aligned rows
#define GROW 340          // G row stride (u32): 1360B, 16B-aligned; gcd(340,32)=4 (bank-safe)
#define NROW 44           // noise row stride (u32): 176B, 16B-aligned rows
#define CONVT 224         // conv threads: (FPB*80 + 512)/8
#define BPB 250           // blocks per batch: 4000/FPB
#define TAB_ELEMS (MT_TOTAL*NCH*64*8)

__device__ __forceinline__ u32 pk2(float a, float b){  // pack 2 f32 -> f16 pair (lo=a, hi=b)
  return __builtin_bit_cast(u32, __builtin_amdgcn_cvt_pkrtz(a, b));
}
__device__ __forceinline__ float dot2(u32 a, u32 b, float c){
#if __has_builtin(__builtin_amdgcn_fdot2)
  return __builtin_amdgcn_fdot2(__builtin_bit_cast(half2v, a), __builtin_bit_cast(half2v, b), c, false);
#else
  half2v x = __builtin_bit_cast(half2v, a), y = __builtin_bit_cast(half2v, b);
  return fmaf((float)x[1], (float)y[1], fmaf((float)x[0], (float)y[0], c));
#endif
}

// ---------------------------------------------------------------------------
// Table in exact MFMA A-frag order: elem((mt*9+c)*64+lane, j) = A[tap][kslot],
// tap = mt*16+(lane&15), kslot = c*32+(lane>>4)*8+j.
// kslot==0 -> hann/513; 1<=kslot<=256 -> (2/513)*hann*cos(2pi*k*(tap-256)/513).
// ---------------------------------------------------------------------------
__global__ void build_table(u16* __restrict__ tab){
  int id = blockIdx.x * blockDim.x + threadIdx.x;
  if (id >= TAB_ELEMS) return;
  int j    = id & 7;
  int lane = (id >> 3) & 63;
  int cc   = (id >> 9) % NCH;
  int mt   = (id >> 9) / NCH;
  int tap  = mt * 16 + (lane & 15);
  int kslot= cc * 32 + (lane >> 4) * 8 + j;
  float val = 0.f;
  if (tap < LF){
    float hann = 0.5f - 0.5f * cosf(6.28318530717958647f * (float)tap / 513.f);
    if (kslot == 0){
      val = hann * (1.f / 513.f);
    } else if (kslot <= 256){
      int rr = (kslot * (tap + 257)) % 513;     // k*(tap-256) mod 513
      val = (2.f / 513.f) * hann * cosf((float)rr * (6.28318530717958647f / 513.f));
    }
  }
  f16 h = (f16)val;
  tab[id] = __builtin_bit_cast(u16, h);
}

// ---------------------------------------------------------------------------
// Fused: stage H/noise(f16) -> MFMA GEMM (fir = T*H^T, single 16-col B tile)
// -> reversed fir in LDS (data slots [32,296)) -> dot2 conv + OLA.
// Geometry: FPB=16/TPB=256 -> LDS 24576B -> 6 blocks/CU = 24 waves/CU.
// Model from R0/R1/R4: dur ~ 1/(resident waves); per-wave duty is pinned
// ~10-15% (latency-bound, compiler-sunk loads) -> residency is the lever.
// XCD swizzle: sample-adjacent logical blocks share an XCD L2 (fringe
// atomics + H/noise stream locality). 8000 % 8 == 0 -> bijective.
// ---------------------------------------------------------------------------
__launch_bounds__(TPB, 6)
__global__ void fused(const float* __restrict__ Hg, const float* __restrict__ noiseg,
                      const u16* __restrict__ tab, float* __restrict__ out){
  __shared__ __align__(16) u32 Gu[FPB * GROW];   // GEMM phase: aliases Hlds u16[16][296]
  __shared__ __align__(16) u32 Nu[FPB * NROW];   // per frame: nA[0..40], [41]=pack(0,n0), [42..43]=0

  const int tid  = threadIdx.x;
  const int lane = tid & 63;
  const int w    = tid >> 6;          // 4 waves
  const int ln15 = lane & 15;
  const int q    = lane >> 4;
  // bijective XCD-chunk swizzle: XCD k owns logical blocks [k*1000,(k+1)*1000)
  const int blk  = (int)(blockIdx.x % 8) * 1000 + (int)(blockIdx.x / 8);
  const int f0   = blk * FPB;

  u16* Hlds = (u16*)Gu;               // [16][296]: slot s = f16(H[s]) s=0..256; 257..287 = 0

  // ---- stage H: 16 rows x 144 u32 tasks = 2304 = 9*256 exact ----
  #pragma unroll
  for (int e = 0; e < 9; ++e){
    int id = tid + TPB * e;
    int r = id / 144, p = id % 144;
    const float* gp = Hg + (size_t)(f0 + r) * NB;
    u32 v = 0u;
    if (p < 128)       v = pk2(gp[2*p], gp[2*p+1]);
    else if (p == 128) v = pk2(gp[256], 0.f);
    *(u32*)&Hlds[r * HROW16 + 2 * p] = v;
  }
  // ---- stage noise: u*2-1 as f16 pairs (640 tasks) ----
  #pragma unroll
  for (int e = 0; e < 3; ++e){
    int id = tid + TPB * e;
    if (id < FPB * 40){
      int r = id / 40, m = id % 40;
      const float* np = noiseg + (size_t)(f0 + r) * FS + 2 * m;
      Nu[r * NROW + m] = pk2(np[0] * 2.f - 1.f, np[1] * 2.f - 1.f);
    }
  }
  if (tid < FPB){
    float n0 = noiseg[(size_t)(f0 + tid) * FS] * 2.f - 1.f;
    Nu[tid * NROW + 40] = 0u;
    Nu[tid * NROW + 41] = pk2(0.f, n0);   // hi half = n0 (even-output n=0 correction)
    Nu[tid * NROW + 42] = 0u;
    Nu[tid * NROW + 43] = 0u;
  }
  __syncthreads();

  // ---- GEMM: fir[tap][frame] = sum_k T[tap][k]*H[frame][k]; 4 waves: {9,8,8,8} mt ----
  // Single 16-column B tile (frames 0..15) -> no wasted MFMA columns.
  const int base = (w == 0) ? 0 : (9 + 8 * (w - 1));
  const int cnt  = (w == 0) ? 9 : 8;
  f32x4 acc[9];
  #pragma unroll
  for (int a = 0; a < 9; ++a) acc[a] = (f32x4){0,0,0,0};
  const half8* tab8 = (const half8*)tab;
  for (int c = 0; c < NCH; ++c){
    half8 bfrag = *(const half8*)&Hlds[ln15 * HROW16 + c*32 + q*8];
    #pragma unroll
    for (int mm = 0; mm < 9; ++mm){
      if (mm < cnt){
        half8 afrag = tab8[((base + mm) * NCH + c) * 64 + lane];
        acc[mm] = __builtin_amdgcn_mfma_f32_16x16x32_f16(afrag, bfrag, acc[mm], 0, 0, 0);
      }
    }
  }
  __syncthreads();   // done reading Hlds; region becomes G

  // ---- epilogue: C/D (col=frame=ln15, row=q*4+reg=tap) -> G reversed f16 pairs ----
  #pragma unroll
  for (int mm = 0; mm < 9; ++mm){
    if (mm < cnt){
      int t0 = (base + mm)*16 + q*4;
      f32x4 v = acc[mm];
      uint2 pk;
      pk.x = pk2(v.w, v.z);
      pk.y = pk2(v.y, v.x);
      *(uint2*)&Gu[ln15 * GROW + (294 - (t0 >> 1))] = pk;   // data slots [32,296)
    }
  }
  // zero-fill pads: u32 slots [0,32) and [296,340) per row = 76/row -> 1216 tasks
  #pragma unroll
  for (int e = 0; e < 5; ++e){
    int id = tid + TPB * e;
    if (id < FPB * 76){
      int r = id / 76, s2 = id % 76;
      Gu[r * GROW + (s2 < 32 ? s2 : 264 + s2)] = 0u;
    }
  }
  __syncthreads();

  // ---- conv + OLA: thread tid -> 8 outputs (block-rel samples 8*tid..8*tid+7) ----
  const bool lastB = (blk % BPB) == (BPB - 1);   // right spill past batch trim -> skip
  if (tid < CONVT && !(lastB && tid >= FPB * 10)){
    const int s8   = tid % 10;             // j0 = 8*s8 + 80*d
    const int fTop = tid / 10;
    const int dMax = (s8 <= 3) ? 7 : 6;    // keep j0 <= 584
    float ac[8];
    #pragma unroll
    for (int r = 0; r < 8; ++r) ac[r] = 0.f;

    #pragma unroll 1
    for (int d = 0; d <= 7; ++d){
      const int frel = fTop - d;
      if (d <= dMax && frel >= 0 && frel < FPB){
        const u32* Gr = Gu + frel * GROW;
        const u32* Nr = Nu + frel * NROW;
        const int V = 296 - 4*s8 - 40*d;   // top pair; V%4==0 -> all uint4 loads 16B-aligned
        // WA[j] = G pair (V-4+j), j=0..43 (static indices after unroll)
        u32 WA[44];
        #pragma unroll
        for (int qq = 0; qq < 11; ++qq){
          uint4 gq = *(const uint4*)(Gr + V - 4 + 4*qq);
          WA[4*qq]   = gq.x; WA[4*qq+1] = gq.y;
          WA[4*qq+2] = gq.z; WA[4*qq+3] = gq.w;
        }
        const u32 n0hi = Nr[41];
        uint4 naNext = *(const uint4*)(Nr);
        #pragma unroll
        for (int k = 0; k < 4; ++k)        // n=0 correction for even r
          ac[2*k] = dot2(n0hi, WA[3-k], ac[2*k]);
        #pragma unroll
        for (int c = 0; c < 10; ++c){
          uint4 naCur = naNext;
          naNext = *(const uint4*)(Nr + 4*c + 4);       // c=9 reads slots 40..43 (padded)
          u32 nAv[5] = {naCur.x, naCur.y, naCur.z, naCur.w, naNext.x};
          #pragma unroll
          for (int i = 0; i < 4; ++i){
            u32 a   = nAv[i];                                          // (n[2m], n[2m+1])
            u32 sft = __builtin_amdgcn_alignbit(nAv[i+1], nAv[i], 16); // (n[2m+1], n[2m+2])
            #pragma unroll
            for (int k = 0; k < 4; ++k){
              ac[2*k]   = dot2(sft, WA[4*c+4+i-k], ac[2*k]);
              ac[2*k+1] = dot2(a,   WA[4*c+3+i-k], ac[2*k+1]);
            }
          }
        }
      }
    }
    const size_t s0 = (size_t)blk * (FPB*FS) + (size_t)tid * 8;  // flat == batched index
    if (tid >= 64 && tid < FPB * 10){      // interior: single-owner vector stores
      *(float4*)&out[s0]     = make_float4(ac[0], ac[1], ac[2], ac[3]);
      *(float4*)&out[s0 + 4] = make_float4(ac[4], ac[5], ac[6], ac[7]);
    } else {                               // fringes shared with neighbor blocks
      #pragma unroll
      for (int r = 0; r < 8; ++r) atomicAdd(&out[s0 + r], ac[r]);
    }
  }
}

extern "C" void kernel_launch(void* const* d_in, const int* in_sizes, int n_in,
                              void* d_out, int out_size, void* d_ws, size_t ws_size,
                              hipStream_t stream){
  const float* Hg     = (const float*)d_in[0];   // [32,4000,257] fp32
  const float* noiseg = (const float*)d_in[1];   // [32,4000,80]  fp32
  float* out = (float*)d_out;                    // [32,320000]   fp32
  u16* tab = (u16*)d_ws;                         // 304128 B

  hipMemsetAsync(d_out, 0, (size_t)out_size * sizeof(float), stream);
  build_table<<<TAB_ELEMS / 256, 256, 0, stream>>>(tab);
  fused<<<(32 * 4000) / FPB, TPB, 0, stream>>>(Hg, noiseg, tab, out);
}

// Round 7
// 474.592 us; speedup vs baseline: 1.1229x; 1.1229x over previous
//
#include <hip/hip_runtime.h>
#include <stdint.h>

typedef unsigned short u16;
typedef unsigned int   u32;
typedef _Float16 f16;
typedef __attribute__((ext_vector_type(2))) _Float16 half2v;
typedef __attribute__((ext_vector_type(8))) _Float16 half8;   // 8 f16 = 4 VGPRs (MFMA A/B frag)
typedef __attribute__((ext_vector_type(4))) float f32x4;      // MFMA C/D frag
typedef __attribute__((ext_vector_type(4))) u32 u32x4;        // ds_read_b128 payload

#define TPB 384           // 6 waves; 3 blocks/CU (LDS-capped) = 18 waves/CU
#define FPB 32            // frames per block; 4000/32=125 -> blocks never straddle batches
#define NB 257
#define LF 513
#define FS 80
#define NCH 9             // K chunks of 32: slots 0..256 = H[0..256], 257..287 = 0
#define MT_TOTAL 33       // 33 tap tiles of 16 = 528 taps (513 real + 15 zero)
#define HROW16 296        // Hlds row stride (u16): 592B, 16B-aligned rows
#define GROW 348          // G row stride (u32): 1392B -> 16B-aligned rows
#define NROW 44           // noise row stride (u32): 176B, 16B-aligned rows
#define TAB_ELEMS (MT_TOTAL*NCH*64*8)

__device__ __forceinline__ u32 pk2(float a, float b){  // pack 2 f32 -> f16 pair (lo=a, hi=b)
  return __builtin_bit_cast(u32, __builtin_amdgcn_cvt_pkrtz(a, b));
}
__device__ __forceinline__ float dot2(u32 a, u32 b, float c){
#if __has_builtin(__builtin_amdgcn_fdot2)
  return __builtin_amdgcn_fdot2(__builtin_bit_cast(half2v, a), __builtin_bit_cast(half2v, b), c, false);
#else
  half2v x = __builtin_bit_cast(half2v, a), y = __builtin_bit_cast(half2v, b);
  return fmaf((float)x[1], (float)y[1], fmaf((float)x[0], (float)y[0], c));
#endif
}

// ---------------------------------------------------------------------------
// Table in exact MFMA A-frag order: elem((mt*9+c)*64+lane, j) = A[tap][kslot],
// tap = mt*16+(lane&15), kslot = c*32+(lane>>4)*8+j.
// ---------------------------------------------------------------------------
__global__ void build_table(u16* __restrict__ tab){
  int id = blockIdx.x * blockDim.x + threadIdx.x;
  if (id >= TAB_ELEMS) return;
  int j    = id & 7;
  int lane = (id >> 3) & 63;
  int cc   = (id >> 9) % NCH;
  int mt   = (id >> 9) / NCH;
  int tap  = mt * 16 + (lane & 15);
  int kslot= cc * 32 + (lane >> 4) * 8 + j;
  float val = 0.f;
  if (tap < LF){
    float hann = 0.5f - 0.5f * cosf(6.28318530717958647f * (float)tap / 513.f);
    if (kslot == 0){
      val = hann * (1.f / 513.f);
    } else if (kslot <= 256){
      int rr = (kslot * (tap + 257)) % 513;     // k*(tap-256) mod 513
      val = (2.f / 513.f) * hann * cosf((float)rr * (6.28318530717958647f / 513.f));
    }
  }
  f16 h = (f16)val;
  tab[id] = __builtin_bit_cast(u16, h);
}

// ---------------------------------------------------------------------------
// Fused: stage H/noise(f16) -> MFMA GEMM (fir = T*H^T) -> reversed fir in LDS
// (G[g] = fir_ext[607-g]) -> dot2 conv + OLA. out[j] = sum_n noise[n]*G[607-j+n].
// Conv: per d-iteration, TWO monolithic asm bursts (reads + s_waitcnt INSIDE
// one asm blob -> outputs architecturally valid at asm end; no stale-spill
// hazard, R6's failure). 2 wait points/d-iter instead of ~22 scattered ones.
// Half A: G quads 0-5 + N quads 0-5 + n0hi (49 regs) -> MAC c=0..4.
// Half B: G quads 5-10 + N quads 5-10 (48 regs)      -> MAC c=5..9.
// ---------------------------------------------------------------------------
__launch_bounds__(TPB, 5)
__global__ void fused(const float* __restrict__ Hg, const float* __restrict__ noiseg,
                      const u16* __restrict__ tab, float* __restrict__ out){
  __shared__ __align__(16) u32 Gu[FPB * GROW];   // GEMM phase: aliases Hlds u16[32][296]
  __shared__ __align__(16) u32 Nu[FPB * NROW];   // per frame: nA[0..40], [41]=pack(0,n0), [42..43]=0

  const int tid  = threadIdx.x;
  const int lane = tid & 63;
  const int w    = tid >> 6;          // 6 waves
  const int ln15 = lane & 15;
  const int q    = lane >> 4;
  const int blk  = blockIdx.x;
  const int f0   = blk * FPB;

  u16* Hlds = (u16*)Gu;               // [32][296]: slot s = f16(H[s]) s=0..256; 257..287 = 0

  // ---- stage H: 32 rows x 144 u32 tasks = 4608 = 12*384 ----
  #pragma unroll
  for (int e = 0; e < 12; ++e){
    int id = tid + TPB * e;
    int r = id / 144, p = id % 144;
    const float* gp = Hg + (size_t)(f0 + r) * NB;
    u32 v = 0u;
    if (p < 128)       v = pk2(gp[2*p], gp[2*p+1]);
    else if (p == 128) v = pk2(gp[256], 0.f);
    *(u32*)&Hlds[r * HROW16 + 2 * p] = v;
  }
  // ---- stage noise: u*2-1 as f16 pairs (1280 tasks) ----
  #pragma unroll
  for (int e = 0; e < 4; ++e){
    int id = tid + TPB * e;
    if (id < FPB * 40){
      int r = id / 40, m = id % 40;
      const float* np = noiseg + (size_t)(f0 + r) * FS + 2 * m;
      Nu[r * NROW + m] = pk2(np[0] * 2.f - 1.f, np[1] * 2.f - 1.f);
    }
  }
  if (tid < FPB){
    float n0 = noiseg[(size_t)(f0 + tid) * FS] * 2.f - 1.f;
    Nu[tid * NROW + 40] = 0u;
    Nu[tid * NROW + 41] = pk2(0.f, n0);   // hi half = n0 (even-output n=0 correction)
    Nu[tid * NROW + 42] = 0u;
    Nu[tid * NROW + 43] = 0u;
  }
  __syncthreads();

  // ---- GEMM: fir[tap][frame] = sum_k T[tap][k]*H[frame][k]; 6 waves: {6,6,6,5,5,5} mt ----
  const int base = (w < 3) ? 6 * w : 18 + 5 * (w - 3);
  const int cnt  = (w < 3) ? 6 : 5;
  f32x4 acc[6][2];
  #pragma unroll
  for (int a = 0; a < 6; ++a){ acc[a][0] = (f32x4){0,0,0,0}; acc[a][1] = (f32x4){0,0,0,0}; }
  const half8* tab8 = (const half8*)tab;
  for (int c = 0; c < NCH; ++c){
    half8 bfrag[2];
    #pragma unroll
    for (int nt = 0; nt < 2; ++nt)
      bfrag[nt] = *(const half8*)&Hlds[(nt*16 + ln15) * HROW16 + c*32 + q*8];
    #pragma unroll
    for (int mm = 0; mm < 6; ++mm){
      if (mm < cnt){
        half8 afrag = tab8[((base + mm) * NCH + c) * 64 + lane];
        #pragma unroll
        for (int nt = 0; nt < 2; ++nt)
          acc[mm][nt] = __builtin_amdgcn_mfma_f32_16x16x32_f16(afrag, bfrag[nt], acc[mm][nt], 0, 0, 0);
      }
    }
  }
  __syncthreads();   // done reading Hlds; region becomes G

  // ---- epilogue: C/D (col=frame, row=q*4+reg=tap) -> G reversed f16 pairs ----
  #pragma unroll
  for (int mm = 0; mm < 6; ++mm){
    if (mm < cnt){
      int t0 = (base + mm)*16 + q*4;
      #pragma unroll
      for (int nt = 0; nt < 2; ++nt){
        int frame = nt*16 + ln15;
        f32x4 v = acc[mm][nt];
        uint2 pk;
        pk.x = pk2(v.w, v.z);
        pk.y = pk2(v.y, v.x);
        *(uint2*)&Gu[frame * GROW + (302 - (t0 >> 1))] = pk;   // G[g]=fir[607-g]
      }
    }
  }
  // zero-fill pads: u32 slots [0,40) and [304,348) per row = 84/row -> 2688 = 7*384
  #pragma unroll
  for (int e = 0; e < 7; ++e){
    int id = tid + TPB * e;
    int r = id / 84, s2 = id % 84;
    Gu[r * GROW + (s2 < 40 ? s2 : 264 + s2)] = 0u;
  }
  __syncthreads();

  // ---- conv + OLA: thread tid -> 8 outputs (block-rel samples 8*tid..8*tid+7) ----
  const bool lastB = (blk % 125) == 124;   // right spill past batch trim -> skip
  if (!(tid >= 320 && lastB)){
    const int s8   = tid % 10;             // j0 = 8*s8 + 80*d
    const int fTop = tid / 10;
    const int dMax = (s8 <= 3) ? 7 : 6;    // keep j0 <= 584
    float ac[8];
    #pragma unroll
    for (int r = 0; r < 8; ++r) ac[r] = 0.f;

    #pragma unroll 1
    for (int d = 0; d <= 7; ++d){
      const int frel = fTop - d;
      if (d <= dMax && frel >= 0 && frel < FPB){
        const u32* Gr = Gu + frel * GROW;
        const u32* Nr = Nu + frel * NROW;
        const int V = 304 - 4*s8 - 40*d;   // top pair; V%4==0 -> all b128 reads 16B-aligned
        const u32 ga = (u32)(uintptr_t)(const void*)(Gr + V - 4);  // LDS byte offset
        const u32 na = (u32)(uintptr_t)(const void*)Nr;

        // ======== burst A: G quads 0-5 (slots V-4..V+19), N quads 0-5, n0hi ========
        u32x4 GA0,GA1,GA2,GA3,GA4,GA5, NA0,NA1,NA2,NA3,NA4,NA5; u32 n0hi;
        asm volatile(
          "ds_read_b128 %0, %13 offset:0\n\t"
          "ds_read_b128 %1, %13 offset:16\n\t"
          "ds_read_b128 %2, %13 offset:32\n\t"
          "ds_read_b128 %3, %13 offset:48\n\t"
          "ds_read_b128 %4, %13 offset:64\n\t"
          "ds_read_b128 %5, %13 offset:80\n\t"
          "ds_read_b128 %6, %14 offset:0\n\t"
          "ds_read_b128 %7, %14 offset:16\n\t"
          "ds_read_b128 %8, %14 offset:32\n\t"
          "ds_read_b128 %9, %14 offset:48\n\t"
          "ds_read_b128 %10, %14 offset:64\n\t"
          "ds_read_b128 %11, %14 offset:80\n\t"
          "ds_read_b32 %12, %14 offset:164\n\t"
          "s_waitcnt lgkmcnt(0)"
          : "=&v"(GA0),"=&v"(GA1),"=&v"(GA2),"=&v"(GA3),"=&v"(GA4),"=&v"(GA5),
            "=&v"(NA0),"=&v"(NA1),"=&v"(NA2),"=&v"(NA3),"=&v"(NA4),"=&v"(NA5),
            "=&v"(n0hi)
          : "v"(ga), "v"(na)
          : "memory");
        __builtin_amdgcn_sched_barrier(0);
        {
          u32 WA[24] = {GA0[0],GA0[1],GA0[2],GA0[3], GA1[0],GA1[1],GA1[2],GA1[3],
                        GA2[0],GA2[1],GA2[2],GA2[3], GA3[0],GA3[1],GA3[2],GA3[3],
                        GA4[0],GA4[1],GA4[2],GA4[3], GA5[0],GA5[1],GA5[2],GA5[3]};
          u32 NS[21] = {NA0[0],NA0[1],NA0[2],NA0[3], NA1[0],NA1[1],NA1[2],NA1[3],
                        NA2[0],NA2[1],NA2[2],NA2[3], NA3[0],NA3[1],NA3[2],NA3[3],
                        NA4[0],NA4[1],NA4[2],NA4[3], NA5[0]};
          #pragma unroll
          for (int k = 0; k < 4; ++k)        // n=0 correction for even r
            ac[2*k] = dot2(n0hi, WA[3-k], ac[2*k]);
          #pragma unroll
          for (int c = 0; c < 5; ++c){
            #pragma unroll
            for (int i = 0; i < 4; ++i){
              u32 a   = NS[4*c+i];
              u32 sft = __builtin_amdgcn_alignbit(NS[4*c+i+1], NS[4*c+i], 16);
              #pragma unroll
              for (int k = 0; k < 4; ++k){
                ac[2*k]   = dot2(sft, WA[4*c+4+i-k], ac[2*k]);
                ac[2*k+1] = dot2(a,   WA[4*c+3+i-k], ac[2*k+1]);
              }
            }
          }
        }
        __builtin_amdgcn_sched_barrier(0);

        // ======== burst B: G quads 5-10 (slots V+16..V+39), N quads 5-10 ========
        u32x4 GB0,GB1,GB2,GB3,GB4,GB5, NB0,NB1,NB2,NB3,NB4,NB5;
        asm volatile(
          "ds_read_b128 %0, %12 offset:80\n\t"
          "ds_read_b128 %1, %12 offset:96\n\t"
          "ds_read_b128 %2, %12 offset:112\n\t"
          "ds_read_b128 %3, %12 offset:128\n\t"
          "ds_read_b128 %4, %12 offset:144\n\t"
          "ds_read_b128 %5, %12 offset:160\n\t"
          "ds_read_b128 %6, %13 offset:80\n\t"
          "ds_read_b128 %7, %13 offset:96\n\t"
          "ds_read_b128 %8, %13 offset:112\n\t"
          "ds_read_b128 %9, %13 offset:128\n\t"
          "ds_read_b128 %10, %13 offset:144\n\t"
          "ds_read_b128 %11, %13 offset:160\n\t"
          "s_waitcnt lgkmcnt(0)"
          : "=&v"(GB0),"=&v"(GB1),"=&v"(GB2),"=&v"(GB3),"=&v"(GB4),"=&v"(GB5),
            "=&v"(NB0),"=&v"(NB1),"=&v"(NB2),"=&v"(NB3),"=&v"(NB4),"=&v"(NB5)
          : "v"(ga), "v"(na)
          : "memory");
        __builtin_amdgcn_sched_barrier(0);
        {
          // WB[x] = G pair (global slot 20+x); NT[x] = noise pair (slot 20+x)
          u32 WB[24] = {GB0[0],GB0[1],GB0[2],GB0[3], GB1[0],GB1[1],GB1[2],GB1[3],
                        GB2[0],GB2[1],GB2[2],GB2[3], GB3[0],GB3[1],GB3[2],GB3[3],
                        GB4[0],GB4[1],GB4[2],GB4[3], GB5[0],GB5[1],GB5[2],GB5[3]};
          u32 NT[21] = {NB0[0],NB0[1],NB0[2],NB0[3], NB1[0],NB1[1],NB1[2],NB1[3],
                        NB2[0],NB2[1],NB2[2],NB2[3], NB3[0],NB3[1],NB3[2],NB3[3],
                        NB4[0],NB4[1],NB4[2],NB4[3], NB5[0]};
          #pragma unroll
          for (int c = 0; c < 5; ++c){       // global c' = c+5
            #pragma unroll
            for (int i = 0; i < 4; ++i){
              u32 a   = NT[4*c+i];
              u32 sft = __builtin_amdgcn_alignbit(NT[4*c+i+1], NT[4*c+i], 16);
              #pragma unroll
              for (int k = 0; k < 4; ++k){
                ac[2*k]   = dot2(sft, WB[4*c+4+i-k], ac[2*k]);
                ac[2*k+1] = dot2(a,   WB[4*c+3+i-k], ac[2*k+1]);
              }
            }
          }
        }
        __builtin_amdgcn_sched_barrier(0);
      }
    }
    const size_t s0 = (size_t)blk * 2560 + (size_t)tid * 8;  // flat == batched index
    if (tid >= 64 && tid < 320){           // interior: single-owner vector stores
      *(float4*)&out[s0]     = make_float4(ac[0], ac[1], ac[2], ac[3]);
      *(float4*)&out[s0 + 4] = make_float4(ac[4], ac[5], ac[6], ac[7]);
    } else {                               // fringes shared with neighbor blocks
      #pragma unroll
      for (int r = 0; r < 8; ++r) atomicAdd(&out[s0 + r], ac[r]);
    }
  }
}

extern "C" void kernel_launch(void* const* d_in, const int* in_sizes, int n_in,
                              void* d_out, int out_size, void* d_ws, size_t ws_size,
                              hipStream_t stream){
  const float* Hg     = (const float*)d_in[0];   // [32,4000,257] fp32
  const float* noiseg = (const float*)d_in[1];   // [32,4000,80]  fp32
  float* out = (float*)d_out;                    // [32,320000]   fp32
  u16* tab = (u16*)d_ws;                         // 304128 B

  hipMemsetAsync(d_out, 0, (size_t)out_size * sizeof(float), stream);
  build_table<<<TAB_ELEMS / 256, 256, 0, stream>>>(tab);
  fused<<<(32 * 4000) / FPB, TPB, 0, stream>>>(Hg, noiseg, tab, out);
}